// Round 1
// baseline (437.257 us; speedup 1.0000x reference)
//
#include <hip/hip_runtime.h>

#define DIM 4096
#define BM 256
#define BN 256
#define BK 64
#define NT (DIM / BK)      // 64 K-tiles
#define THREADS 512        // 8 waves: 2 (M) x 4 (N)

typedef _Float16 half8 __attribute__((ext_vector_type(8)));
typedef _Float16 half4v __attribute__((ext_vector_type(4)));
typedef float floatx4 __attribute__((ext_vector_type(4)));

// Async global->LDS, 16B per lane. LDS dest is wave-uniform base + lane*16.
__device__ __forceinline__ void async_copy16(const _Float16* g, _Float16* l) {
    __builtin_amdgcn_global_load_lds(
        (const __attribute__((address_space(1))) void*)g,
        (__attribute__((address_space(3))) void*)l,
        16, 0, 0);
}

__device__ __forceinline__ void cfence() { asm volatile("" ::: "memory"); }
__device__ __forceinline__ void bar() { cfence(); __builtin_amdgcn_s_barrier(); cfence(); }

// 256x256 tile, BK=64, 8-phase schedule with counted vmcnt (T2+T3+T4+T5).
// LDS: [dbuf][A/B][half(128x64)] = 128 KiB, st_16x32 XOR swizzle
// (16B-chunk index ^= ((chunk>>5)&1)<<1; i.e. byte ^= ((byte>>9)&1)<<5).
// global_load_lds writes linearly, so the *global source* is pre-swizzled and
// the ds_read applies the same involution (both-sides rule).
//
// Per K-tile T (slot s=T&1) the 4 phases compute quadrants (0,0),(0,1),(1,0),(1,1)
// of each wave's 128x64 output and stage (stream order):
//   ph1: K(T+1).A1 -> lds[s^1][A][1]   (other slot, no conflict)
//   ph2: K(T+2).B0 -> lds[s][B][0]     (B0 fully read in ph1)
//   ph3: K(T+2).B1 -> lds[s][B][1]     (B1 fully read by ph2)
//   ph4: K(T+2).A0 -> lds[s][A][0]     (A0 fully read by ph3)
// vmcnt(6) once per K-tile (3 half-tiles = 6 loads in flight); vmcnt(0) only
// for the last two tiles. Never drained mid-loop.
template <bool QUANT>
__global__ __launch_bounds__(THREADS, 2)
void gemm_bt(const _Float16* __restrict__ A,
             const _Float16* __restrict__ B,
             const float* __restrict__ cb,
             _Float16* __restrict__ Yq,
             float* __restrict__ C)
{
    __shared__ _Float16 lds[2][2][2][128 * BK];   // 128 KiB
    __shared__ float    s_bnd[15];
    __shared__ _Float16 s_cb[16];

    const int t    = threadIdx.x;
    const int lane = t & 63;
    const int wid  = t >> 6;            // 0..7
    const int wm   = (wid >> 2) * 128;  // wave M origin in tile
    const int wn   = (wid & 3) * 64;    // wave N origin in tile
    const int am   = wid >> 2;          // A half this wave reads
    const int bh   = (wid >> 1) & 1;    // B half this wave reads
    const int bro  = (wid & 1) * 64;    // row offset inside B half
    const bool earlyB = (bh == 0);      // B-half0 is overwritten at ph2 -> read all B in ph1

    // XCD-aware bijective swizzle (nwg = 256, 256 % 8 == 0)
    const int bid = blockIdx.y * gridDim.x + blockIdx.x;
    const int swz = (bid & 7) * (256 / 8) + (bid >> 3);
    const int bm  = (swz & 15) * BM;
    const int bn  = (swz >> 4) * BN;

    if (QUANT) {
        if (t < 16) s_cb[t]  = (_Float16)cb[t];
        if (t < 15) s_bnd[t] = 0.5f * (cb[t] + cb[t + 1]);
    }

    // Staging: one 128x64 half-tile = 1024 16B chunks; thread t owns physical
    // chunks t and 512+t. Pre-swizzle the global source so swizzled reads work.
    const int pc0 = t, pc1 = 512 + t;
    const int lc0 = pc0 ^ (((pc0 >> 5) & 1) << 1);
    const int lc1 = pc1 ^ (((pc1 >> 5) & 1) << 1);
    const int goff0 = (lc0 >> 3) * DIM + (lc0 & 7) * 8;   // halves
    const int goff1 = (lc1 >> 3) * DIM + (lc1 & 7) * 8;

    auto stage = [&](const _Float16* srcrow0, _Float16* reg) {
        async_copy16(srcrow0 + goff0, reg + t * 8);
        async_copy16(srcrow0 + goff1, reg + (512 + t) * 8);
    };

    // MFMA 16x16x32 f16 fragment: elem[k = (lane>>4)*8 + j] of row (lane&15).
    // Swizzle inverse on read: col-chunk (ks*4+kg) ^ (((row>>2)&1)<<1); row bit2
    // equals frow bit2, so the XOR term is a per-lane constant.
    const int frow  = lane & 15;
    const int kg    = lane >> 4;
    const int xr    = ((frow >> 2) & 1) << 1;
    const int koff0 = ((0 + kg) ^ xr) * 8;   // ks = 0
    const int koff1 = ((4 + kg) ^ xr) * 8;   // ks = 1

    floatx4 acc[8][4] = {};

    // Prologue: K0 fully (B0,B1,A0,A1) + K1 (B0,B1,A0) = 14 loads; wait K0.
    stage(B + (size_t)bn * DIM,               &lds[0][1][0][0]);
    stage(B + (size_t)(bn + 128) * DIM,       &lds[0][1][1][0]);
    stage(A + (size_t)bm * DIM,               &lds[0][0][0][0]);
    stage(A + (size_t)(bm + 128) * DIM,       &lds[0][0][1][0]);
    stage(B + (size_t)bn * DIM + BK,          &lds[1][1][0][0]);
    stage(B + (size_t)(bn + 128) * DIM + BK,  &lds[1][1][1][0]);
    stage(A + (size_t)bm * DIM + BK,          &lds[1][0][0][0]);
    asm volatile("s_waitcnt vmcnt(6)" ::: "memory");
    bar();

#pragma unroll 2
    for (int T = 0; T < NT; ++T) {
        const int s  = T & 1;
        const int ns = s ^ 1;
        const _Float16* Ar = &lds[s][0][am][0];
        const _Float16* Br = &lds[s][1][bh][0];
        const size_t k1 = (size_t)(T + 1) * BK;
        const size_t k2 = (size_t)(T + 2) * BK;

#define LDA8(i_, ks_) (*(const half8*)(Ar + ((i_) * 16 + frow) * BK + ((ks_) ? koff1 : koff0)))
#define LDB8(j_, ks_) (*(const half8*)(Br + (bro + (j_) * 16 + frow) * BK + ((ks_) ? koff1 : koff0)))

        half8 aF[2][4], bF[2][4];

        // ---------------- phase 1: quadrant (0,0) ----------------
#pragma unroll
        for (int i = 0; i < 4; ++i) { aF[0][i] = LDA8(i, 0); aF[1][i] = LDA8(i, 1); }
        bF[0][0] = LDB8(0, 0); bF[1][0] = LDB8(0, 1);
        bF[0][1] = LDB8(1, 0); bF[1][1] = LDB8(1, 1);
        if (earlyB) {   // must finish B-half0 before its ph2 overwrite
            bF[0][2] = LDB8(2, 0); bF[1][2] = LDB8(2, 1);
            bF[0][3] = LDB8(3, 0); bF[1][3] = LDB8(3, 1);
        }
        if (T + 1 < NT) stage(A + (size_t)(bm + 128) * DIM + k1, &lds[ns][0][1][0]);
        bar();
        asm volatile("s_waitcnt lgkmcnt(0)" ::: "memory");
        __builtin_amdgcn_sched_barrier(0);
        __builtin_amdgcn_s_setprio(1);
#pragma unroll
        for (int i = 0; i < 4; ++i)
#pragma unroll
            for (int j = 0; j < 2; ++j) {
                acc[i][j] = __builtin_amdgcn_mfma_f32_16x16x32_f16(aF[0][i], bF[0][j], acc[i][j], 0, 0, 0);
                acc[i][j] = __builtin_amdgcn_mfma_f32_16x16x32_f16(aF[1][i], bF[1][j], acc[i][j], 0, 0, 0);
            }
        __builtin_amdgcn_s_setprio(0);
        bar();

        // ---------------- phase 2: quadrant (0,1) ----------------
        if (!earlyB) {
            bF[0][2] = LDB8(2, 0); bF[1][2] = LDB8(2, 1);
            bF[0][3] = LDB8(3, 0); bF[1][3] = LDB8(3, 1);
        }
        if (T + 2 < NT) stage(B + (size_t)bn * DIM + k2, &lds[s][1][0][0]);
        bar();
        asm volatile("s_waitcnt lgkmcnt(0)" ::: "memory");
        __builtin_amdgcn_sched_barrier(0);
        __builtin_amdgcn_s_setprio(1);
#pragma unroll
        for (int i = 0; i < 4; ++i)
#pragma unroll
            for (int j = 0; j < 2; ++j) {
                acc[i][2 + j] = __builtin_amdgcn_mfma_f32_16x16x32_f16(aF[0][i], bF[0][2 + j], acc[i][2 + j], 0, 0, 0);
                acc[i][2 + j] = __builtin_amdgcn_mfma_f32_16x16x32_f16(aF[1][i], bF[1][2 + j], acc[i][2 + j], 0, 0, 0);
            }
        __builtin_amdgcn_s_setprio(0);
        bar();

        // ---------------- phase 3: quadrant (1,0) ----------------
#pragma unroll
        for (int i = 0; i < 4; ++i) { aF[0][i] = LDA8(4 + i, 0); aF[1][i] = LDA8(4 + i, 1); }
        if (T + 2 < NT) stage(B + (size_t)(bn + 128) * DIM + k2, &lds[s][1][1][0]);
        bar();
        asm volatile("s_waitcnt lgkmcnt(0)" ::: "memory");
        __builtin_amdgcn_sched_barrier(0);
        __builtin_amdgcn_s_setprio(1);
#pragma unroll
        for (int i = 0; i < 4; ++i)
#pragma unroll
            for (int j = 0; j < 2; ++j) {
                acc[4 + i][j] = __builtin_amdgcn_mfma_f32_16x16x32_f16(aF[0][i], bF[0][j], acc[4 + i][j], 0, 0, 0);
                acc[4 + i][j] = __builtin_amdgcn_mfma_f32_16x16x32_f16(aF[1][i], bF[1][j], acc[4 + i][j], 0, 0, 0);
            }
        __builtin_amdgcn_s_setprio(0);
        bar();

        // ---------------- phase 4: quadrant (1,1) ----------------
        if (T + 2 < NT) stage(A + (size_t)bm * DIM + k2, &lds[s][0][0][0]);
        bar();
        __builtin_amdgcn_s_setprio(1);
#pragma unroll
        for (int i = 0; i < 4; ++i)
#pragma unroll
            for (int j = 0; j < 2; ++j) {
                acc[4 + i][2 + j] = __builtin_amdgcn_mfma_f32_16x16x32_f16(aF[0][i], bF[0][2 + j], acc[4 + i][2 + j], 0, 0, 0);
                acc[4 + i][2 + j] = __builtin_amdgcn_mfma_f32_16x16x32_f16(aF[1][i], bF[1][2 + j], acc[4 + i][2 + j], 0, 0, 0);
            }
        __builtin_amdgcn_s_setprio(0);
        // Counted vmcnt ONCE per K-tile: next K-tile fully landed, 3 half-tiles
        // (6 loads) still in flight. Drain only for the final tiles.
        if (T < NT - 2) asm volatile("s_waitcnt vmcnt(6)" ::: "memory");
        else            asm volatile("s_waitcnt vmcnt(0)" ::: "memory");
        bar();
#undef LDA8
#undef LDB8
    }

    // D layout: col = lane&15, row = (lane>>4)*4 + reg  [m89-verified]
    if (QUANT) {
        float bnd[15];
#pragma unroll
        for (int b = 0; b < 15; ++b) bnd[b] = s_bnd[b];
#pragma unroll
        for (int i = 0; i < 8; ++i) {
            const int gr0 = bm + wm + i * 16 + (lane >> 4) * 4;
#pragma unroll
            for (int j = 0; j < 4; ++j) {
                const int gc = bn + wn + j * 16 + frow;
#pragma unroll
                for (int rr = 0; rr < 4; ++rr) {
                    const float v = acc[i][j][rr];
                    int idx = 0;
#pragma unroll
                    for (int b = 0; b < 15; ++b) idx += (v > bnd[b]) ? 1 : 0;
                    Yq[(size_t)(gr0 + rr) * DIM + gc] = s_cb[idx];
                }
            }
        }
    } else {
#pragma unroll
        for (int i = 0; i < 8; ++i) {
            const int gr0 = bm + wm + i * 16 + (lane >> 4) * 4;
#pragma unroll
            for (int j = 0; j < 4; ++j) {
                const int gc = bn + wn + j * 16 + frow;
#pragma unroll
                for (int rr = 0; rr < 4; ++rr)
                    C[(size_t)(gr0 + rr) * DIM + gc] = acc[i][j][rr];
            }
        }
    }
}

// x (fp32) -> f16, 4 elements/thread
__global__ void convert_f16(const float* __restrict__ in, _Float16* __restrict__ out)
{
    const size_t i = ((size_t)blockIdx.x * 256 + threadIdx.x) * 4;
    const float4 v = *(const float4*)(in + i);
    half4v h;
    h.x = (_Float16)v.x; h.y = (_Float16)v.y; h.z = (_Float16)v.z; h.w = (_Float16)v.w;
    *(half4v*)(out + i) = h;
}

// Pi (fp32) -> Pi_f16 (straight) and PiT_f16 (transposed).
__global__ void prep_pi(const float* __restrict__ Pi,
                        _Float16* __restrict__ Pif,
                        _Float16* __restrict__ PiT)
{
    __shared__ _Float16 tile[64][68];
    const int t  = threadIdx.x;
    const int r0 = t >> 4;
    const int c4 = (t & 15) * 4;
    const int y0 = blockIdx.y * 64;
    const int x0 = blockIdx.x * 64;
#pragma unroll
    for (int ii = 0; ii < 4; ++ii) {
        const int r = ii * 16 + r0;
        const float4 v = *(const float4*)(Pi + (size_t)(y0 + r) * DIM + x0 + c4);
        half4v h;
        h.x = (_Float16)v.x; h.y = (_Float16)v.y; h.z = (_Float16)v.z; h.w = (_Float16)v.w;
        *(half4v*)(Pif + (size_t)(y0 + r) * DIM + x0 + c4) = h;
        tile[c4 + 0][r] = h.x;
        tile[c4 + 1][r] = h.y;
        tile[c4 + 2][r] = h.z;
        tile[c4 + 3][r] = h.w;
    }
    __syncthreads();
#pragma unroll
    for (int ii = 0; ii < 4; ++ii) {
        const int c = ii * 16 + r0;
        *(half4v*)(PiT + (size_t)(x0 + c) * DIM + y0 + c4) = *(const half4v*)&tile[c][c4];
    }
}

extern "C" void kernel_launch(void* const* d_in, const int* in_sizes, int n_in,
                              void* d_out, int out_size, void* d_ws, size_t ws_size,
                              hipStream_t stream)
{
    (void)in_sizes; (void)n_in; (void)out_size; (void)ws_size;
    const float* x  = (const float*)d_in[0];
    const float* Pi = (const float*)d_in[1];
    const float* cb = (const float*)d_in[2];
    float* out = (float*)d_out;

    char* ws = (char*)d_ws;
    const size_t MB32 = (size_t)DIM * DIM * sizeof(_Float16);  // 32 MiB
    _Float16* xh  = (_Float16*)(ws);
    _Float16* pih = (_Float16*)(ws + MB32);
    _Float16* pit = (_Float16*)(ws + 2 * MB32);
    _Float16* yh  = (_Float16*)(ws + 3 * MB32);

    convert_f16<<<dim3(DIM * DIM / (256 * 4)), dim3(256), 0, stream>>>(x, xh);
    prep_pi<<<dim3(DIM / 64, DIM / 64), dim3(256), 0, stream>>>(Pi, pih, pit);

    // GEMM1: y = x @ Pi^T, fused Lloyd-Max quantize -> y_tilde (f16)
    gemm_bt<true><<<dim3(DIM / BM, DIM / BN), dim3(THREADS), 0, stream>>>(xh, pih, cb, yh, nullptr);
    // GEMM2: x_tilde = y_tilde @ Pi  ==  "bt" GEMM against PiT
    gemm_bt<false><<<dim3(DIM / BM, DIM / BN), dim3(THREADS), 0, stream>>>(yh, pit, cb, nullptr, out);
}

// Round 2
// 416.680 us; speedup vs baseline: 1.0494x; 1.0494x over previous
//
#include <hip/hip_runtime.h>

#define DIM 4096
#define BM 256
#define BN 256
#define BK 64
#define NT (DIM / BK)      // 64 K-tiles
#define THREADS 512        // 8 waves: 2 (M) x 4 (N)

typedef _Float16 half8 __attribute__((ext_vector_type(8)));
typedef _Float16 half4v __attribute__((ext_vector_type(4)));
typedef float floatx4 __attribute__((ext_vector_type(4)));

// Async global->LDS, 16B per lane. LDS dest is wave-uniform base + lane*16.
__device__ __forceinline__ void async_copy16(const _Float16* g, _Float16* l) {
    __builtin_amdgcn_global_load_lds(
        (const __attribute__((address_space(1))) void*)g,
        (__attribute__((address_space(3))) void*)l,
        16, 0, 0);
}

__device__ __forceinline__ void cfence() { asm volatile("" ::: "memory"); }
__device__ __forceinline__ void bar() { cfence(); __builtin_amdgcn_s_barrier(); cfence(); }

// 256x256 tile, BK=64, 8-phase schedule with counted vmcnt (T3+T4+T5).
// LDS: [dbuf][A/B][half(128x64)] = 128 KiB.
// Swizzle: row = 64 halves = 128 B = exactly 32 banks, so bank depends only on
// the 16B column-chunk. Full 3-bit XOR (chunk ^ (row&7)) spreads the 8 chunks
// across all 32 banks for the fragment read pattern (kg in 0..3 x frow in
// 0..15) -> measured 0 conflicts in the 128^2 kernel with this exact pattern.
// global_load_lds writes linearly, so the *global source* is pre-swizzled and
// the ds_read applies the same involution (both-sides rule).
//
// Per K-tile T (slot s=T&1) the 4 phases compute quadrants (0,0),(0,1),(1,0),(1,1)
// of each wave's 128x64 output and stage (stream order):
//   ph1: K(T+1).A1 -> lds[s^1][A][1]   (other slot, no conflict)
//   ph2: K(T+2).B0 -> lds[s][B][0]     (B0 fully read in ph1)
//   ph3: K(T+2).B1 -> lds[s][B][1]     (B1 fully read by ph2)
//   ph4: K(T+2).A0 -> lds[s][A][0]     (A0 fully read by ph3)
// vmcnt(6) once per K-tile (3 half-tiles = 6 loads in flight); vmcnt(0) only
// for the last two tiles. Never drained mid-loop.
template <bool QUANT>
__global__ __launch_bounds__(THREADS, 2)
void gemm_bt(const _Float16* __restrict__ A,
             const _Float16* __restrict__ B,
             const float* __restrict__ cb,
             _Float16* __restrict__ Yq,
             float* __restrict__ C)
{
    __shared__ _Float16 lds[2][2][2][128 * BK];   // 128 KiB
    __shared__ float    s_bnd[15];
    __shared__ _Float16 s_cb[16];

    const int t    = threadIdx.x;
    const int lane = t & 63;
    const int wid  = t >> 6;            // 0..7
    const int wm   = (wid >> 2) * 128;  // wave M origin in tile
    const int wn   = (wid & 3) * 64;    // wave N origin in tile
    const int am   = wid >> 2;          // A half this wave reads
    const int bh   = (wid >> 1) & 1;    // B half this wave reads
    const int bro  = (wid & 1) * 64;    // row offset inside B half
    const bool earlyB = (bh == 0);      // B-half0 is overwritten at ph2 -> read all B in ph1

    // XCD-aware bijective swizzle (nwg = 256, 256 % 8 == 0)
    const int bid = blockIdx.y * gridDim.x + blockIdx.x;
    const int swz = (bid & 7) * (256 / 8) + (bid >> 3);
    const int bm  = (swz & 15) * BM;
    const int bn  = (swz >> 4) * BN;

    if (QUANT) {
        if (t < 16) s_cb[t]  = (_Float16)cb[t];
        if (t < 15) s_bnd[t] = 0.5f * (cb[t] + cb[t + 1]);
    }

    // Staging: one 128x64 half-tile = 1024 16B chunks; thread t owns physical
    // chunks t and 512+t. Physical chunk p holds logical (row = p>>3,
    // col = (p&7) ^ ((p>>3)&7)) -> pre-swizzle the global source.
    const int pc0 = t, pc1 = 512 + t;
    const int goff0 = (pc0 >> 3) * DIM + ((pc0 & 7) ^ ((pc0 >> 3) & 7)) * 8;  // halves
    const int goff1 = (pc1 >> 3) * DIM + ((pc1 & 7) ^ ((pc1 >> 3) & 7)) * 8;

    auto stage = [&](const _Float16* srcrow0, _Float16* reg) {
        async_copy16(srcrow0 + goff0, reg + t * 8);
        async_copy16(srcrow0 + goff1, reg + (512 + t) * 8);
    };

    // MFMA 16x16x32 f16 fragment: elem[k = (lane>>4)*8 + j] of row (lane&15).
    // Swizzle inverse on read: physical col = (ks*4+kg) ^ (row&7); row&7 ==
    // frow&7 for all sub-tiles (offsets are multiples of 8/16/64), so the XOR
    // is a per-lane constant. 4+kg <= 7 keeps the XOR closed in [0,8).
    const int frow  = lane & 15;
    const int kg    = lane >> 4;
    const int xr    = frow & 7;
    const int koff0 = ((0 + kg) ^ xr) * 8;   // ks = 0
    const int koff1 = ((4 + kg) ^ xr) * 8;   // ks = 1

    floatx4 acc[8][4] = {};

    // Prologue: K0 fully (B0,B1,A0,A1) + K1 (B0,B1,A0) = 14 loads; wait K0.
    stage(B + (size_t)bn * DIM,               &lds[0][1][0][0]);
    stage(B + (size_t)(bn + 128) * DIM,       &lds[0][1][1][0]);
    stage(A + (size_t)bm * DIM,               &lds[0][0][0][0]);
    stage(A + (size_t)(bm + 128) * DIM,       &lds[0][0][1][0]);
    stage(B + (size_t)bn * DIM + BK,          &lds[1][1][0][0]);
    stage(B + (size_t)(bn + 128) * DIM + BK,  &lds[1][1][1][0]);
    stage(A + (size_t)bm * DIM + BK,          &lds[1][0][0][0]);
    asm volatile("s_waitcnt vmcnt(6)" ::: "memory");
    bar();

#pragma unroll 2
    for (int T = 0; T < NT; ++T) {
        const int s  = T & 1;
        const int ns = s ^ 1;
        const _Float16* Ar = &lds[s][0][am][0];
        const _Float16* Br = &lds[s][1][bh][0];
        const size_t k1 = (size_t)(T + 1) * BK;
        const size_t k2 = (size_t)(T + 2) * BK;

#define LDA8(i_, ks_) (*(const half8*)(Ar + ((i_) * 16 + frow) * BK + ((ks_) ? koff1 : koff0)))
#define LDB8(j_, ks_) (*(const half8*)(Br + (bro + (j_) * 16 + frow) * BK + ((ks_) ? koff1 : koff0)))

        half8 aF[2][4], bF[2][4];

        // ---------------- phase 1: quadrant (0,0) ----------------
#pragma unroll
        for (int i = 0; i < 4; ++i) { aF[0][i] = LDA8(i, 0); aF[1][i] = LDA8(i, 1); }
        bF[0][0] = LDB8(0, 0); bF[1][0] = LDB8(0, 1);
        bF[0][1] = LDB8(1, 0); bF[1][1] = LDB8(1, 1);
        if (earlyB) {   // must finish B-half0 before its ph2 overwrite
            bF[0][2] = LDB8(2, 0); bF[1][2] = LDB8(2, 1);
            bF[0][3] = LDB8(3, 0); bF[1][3] = LDB8(3, 1);
        }
        if (T + 1 < NT) stage(A + (size_t)(bm + 128) * DIM + k1, &lds[ns][0][1][0]);
        bar();
        asm volatile("s_waitcnt lgkmcnt(0)" ::: "memory");
        __builtin_amdgcn_sched_barrier(0);
        __builtin_amdgcn_s_setprio(1);
#pragma unroll
        for (int i = 0; i < 4; ++i)
#pragma unroll
            for (int j = 0; j < 2; ++j) {
                acc[i][j] = __builtin_amdgcn_mfma_f32_16x16x32_f16(aF[0][i], bF[0][j], acc[i][j], 0, 0, 0);
                acc[i][j] = __builtin_amdgcn_mfma_f32_16x16x32_f16(aF[1][i], bF[1][j], acc[i][j], 0, 0, 0);
            }
        __builtin_amdgcn_s_setprio(0);
        bar();

        // ---------------- phase 2: quadrant (0,1) ----------------
        if (!earlyB) {
            bF[0][2] = LDB8(2, 0); bF[1][2] = LDB8(2, 1);
            bF[0][3] = LDB8(3, 0); bF[1][3] = LDB8(3, 1);
        }
        if (T + 2 < NT) stage(B + (size_t)bn * DIM + k2, &lds[s][1][0][0]);
        bar();
        asm volatile("s_waitcnt lgkmcnt(0)" ::: "memory");
        __builtin_amdgcn_sched_barrier(0);
        __builtin_amdgcn_s_setprio(1);
#pragma unroll
        for (int i = 0; i < 4; ++i)
#pragma unroll
            for (int j = 0; j < 2; ++j) {
                acc[i][2 + j] = __builtin_amdgcn_mfma_f32_16x16x32_f16(aF[0][i], bF[0][2 + j], acc[i][2 + j], 0, 0, 0);
                acc[i][2 + j] = __builtin_amdgcn_mfma_f32_16x16x32_f16(aF[1][i], bF[1][2 + j], acc[i][2 + j], 0, 0, 0);
            }
        __builtin_amdgcn_s_setprio(0);
        bar();

        // ---------------- phase 3: quadrant (1,0) ----------------
#pragma unroll
        for (int i = 0; i < 4; ++i) { aF[0][i] = LDA8(4 + i, 0); aF[1][i] = LDA8(4 + i, 1); }
        if (T + 2 < NT) stage(B + (size_t)(bn + 128) * DIM + k2, &lds[s][1][1][0]);
        bar();
        asm volatile("s_waitcnt lgkmcnt(0)" ::: "memory");
        __builtin_amdgcn_sched_barrier(0);
        __builtin_amdgcn_s_setprio(1);
#pragma unroll
        for (int i = 0; i < 4; ++i)
#pragma unroll
            for (int j = 0; j < 2; ++j) {
                acc[4 + i][j] = __builtin_amdgcn_mfma_f32_16x16x32_f16(aF[0][i], bF[0][j], acc[4 + i][j], 0, 0, 0);
                acc[4 + i][j] = __builtin_amdgcn_mfma_f32_16x16x32_f16(aF[1][i], bF[1][j], acc[4 + i][j], 0, 0, 0);
            }
        __builtin_amdgcn_s_setprio(0);
        bar();

        // ---------------- phase 4: quadrant (1,1) ----------------
        if (T + 2 < NT) stage(A + (size_t)bm * DIM + k2, &lds[s][0][0][0]);
        bar();
        __builtin_amdgcn_s_setprio(1);
#pragma unroll
        for (int i = 0; i < 4; ++i)
#pragma unroll
            for (int j = 0; j < 2; ++j) {
                acc[4 + i][2 + j] = __builtin_amdgcn_mfma_f32_16x16x32_f16(aF[0][i], bF[0][2 + j], acc[4 + i][2 + j], 0, 0, 0);
                acc[4 + i][2 + j] = __builtin_amdgcn_mfma_f32_16x16x32_f16(aF[1][i], bF[1][2 + j], acc[4 + i][2 + j], 0, 0, 0);
            }
        __builtin_amdgcn_s_setprio(0);
        // Counted vmcnt ONCE per K-tile: next K-tile fully landed, 3 half-tiles
        // (6 loads) still in flight. Drain only for the final tiles.
        if (T < NT - 2) asm volatile("s_waitcnt vmcnt(6)" ::: "memory");
        else            asm volatile("s_waitcnt vmcnt(0)" ::: "memory");
        bar();
#undef LDA8
#undef LDB8
    }

    // D layout: col = lane&15, row = (lane>>4)*4 + reg  [m89-verified]
    if (QUANT) {
        float bnd[15];
#pragma unroll
        for (int b = 0; b < 15; ++b) bnd[b] = s_bnd[b];
#pragma unroll
        for (int i = 0; i < 8; ++i) {
            const int gr0 = bm + wm + i * 16 + (lane >> 4) * 4;
#pragma unroll
            for (int j = 0; j < 4; ++j) {
                const int gc = bn + wn + j * 16 + frow;
#pragma unroll
                for (int rr = 0; rr < 4; ++rr) {
                    const float v = acc[i][j][rr];
                    int idx = 0;
#pragma unroll
                    for (int b = 0; b < 15; ++b) idx += (v > bnd[b]) ? 1 : 0;
                    Yq[(size_t)(gr0 + rr) * DIM + gc] = s_cb[idx];
                }
            }
        }
    } else {
#pragma unroll
        for (int i = 0; i < 8; ++i) {
            const int gr0 = bm + wm + i * 16 + (lane >> 4) * 4;
#pragma unroll
            for (int j = 0; j < 4; ++j) {
                const int gc = bn + wn + j * 16 + frow;
#pragma unroll
                for (int rr = 0; rr < 4; ++rr)
                    C[(size_t)(gr0 + rr) * DIM + gc] = acc[i][j][rr];
            }
        }
    }
}

// x (fp32) -> f16, 4 elements/thread
__global__ void convert_f16(const float* __restrict__ in, _Float16* __restrict__ out)
{
    const size_t i = ((size_t)blockIdx.x * 256 + threadIdx.x) * 4;
    const float4 v = *(const float4*)(in + i);
    half4v h;
    h.x = (_Float16)v.x; h.y = (_Float16)v.y; h.z = (_Float16)v.z; h.w = (_Float16)v.w;
    *(half4v*)(out + i) = h;
}

// Pi (fp32) -> Pi_f16 (straight) and PiT_f16 (transposed).
__global__ void prep_pi(const float* __restrict__ Pi,
                        _Float16* __restrict__ Pif,
                        _Float16* __restrict__ PiT)
{
    __shared__ _Float16 tile[64][68];
    const int t  = threadIdx.x;
    const int r0 = t >> 4;
    const int c4 = (t & 15) * 4;
    const int y0 = blockIdx.y * 64;
    const int x0 = blockIdx.x * 64;
#pragma unroll
    for (int ii = 0; ii < 4; ++ii) {
        const int r = ii * 16 + r0;
        const float4 v = *(const float4*)(Pi + (size_t)(y0 + r) * DIM + x0 + c4);
        half4v h;
        h.x = (_Float16)v.x; h.y = (_Float16)v.y; h.z = (_Float16)v.z; h.w = (_Float16)v.w;
        *(half4v*)(Pif + (size_t)(y0 + r) * DIM + x0 + c4) = h;
        tile[c4 + 0][r] = h.x;
        tile[c4 + 1][r] = h.y;
        tile[c4 + 2][r] = h.z;
        tile[c4 + 3][r] = h.w;
    }
    __syncthreads();
#pragma unroll
    for (int ii = 0; ii < 4; ++ii) {
        const int c = ii * 16 + r0;
        *(half4v*)(PiT + (size_t)(x0 + c) * DIM + y0 + c4) = *(const half4v*)&tile[c][c4];
    }
}

extern "C" void kernel_launch(void* const* d_in, const int* in_sizes, int n_in,
                              void* d_out, int out_size, void* d_ws, size_t ws_size,
                              hipStream_t stream)
{
    (void)in_sizes; (void)n_in; (void)out_size; (void)ws_size;
    const float* x  = (const float*)d_in[0];
    const float* Pi = (const float*)d_in[1];
    const float* cb = (const float*)d_in[2];
    float* out = (float*)d_out;

    char* ws = (char*)d_ws;
    const size_t MB32 = (size_t)DIM * DIM * sizeof(_Float16);  // 32 MiB
    _Float16* xh  = (_Float16*)(ws);
    _Float16* pih = (_Float16*)(ws + MB32);
    _Float16* pit = (_Float16*)(ws + 2 * MB32);
    _Float16* yh  = (_Float16*)(ws + 3 * MB32);

    convert_f16<<<dim3(DIM * DIM / (256 * 4)), dim3(256), 0, stream>>>(x, xh);
    prep_pi<<<dim3(DIM / 64, DIM / 64), dim3(256), 0, stream>>>(Pi, pih, pit);

    // GEMM1: y = x @ Pi^T, fused Lloyd-Max quantize -> y_tilde (f16)
    gemm_bt<true><<<dim3(DIM / BM, DIM / BN), dim3(THREADS), 0, stream>>>(xh, pih, cb, yh, nullptr);
    // GEMM2: x_tilde = y_tilde @ Pi  ==  "bt" GEMM against PiT
    gemm_bt<false><<<dim3(DIM / BM, DIM / BN), dim3(THREADS), 0, stream>>>(yh, pit, cb, nullptr, out);
}